// Round 11
// baseline (274.295 us; speedup 1.0000x reference)
//
#include <hip/hip_runtime.h>

#define N_NODES 100000
#define N_EDGES 1280000
#define D 64
#define NPAD 102400
#define CAP 48              // per-node CSR capacity; rows 192 B (64 B-aligned)
#define NBUCK 391           // buckets of 256 nodes: 391*256 = 100096
#define BUFCAP 4096         // per-bucket edge buffer capacity (avg 3276, +12 sigma)
#define NTILES 3125         // 32-node tiles, 3125*32 = 100000 exactly
#define PERSIST 2048        // 8 blocks/CU * 256 CUs

typedef __attribute__((ext_vector_type(8))) short bf16x8;
typedef __attribute__((ext_vector_type(4))) float f32x4;

__device__ __forceinline__ unsigned short f2bf(float f) {
    union { float f; unsigned u; } c; c.f = f;
    unsigned u = c.u;
    return (unsigned short)((u + 0x7FFF + ((u >> 16) & 1)) >> 16);   // RNE
}
__device__ __forceinline__ float bf2f(unsigned short s) {
    union { unsigned u; float f; } c; c.u = ((unsigned)s) << 16;
    return c.f;
}

// ---- fused convert: x -> bf16, 2 zero rows, 4 weight matrices -> bf16 ---
#define XQ (N_NODES * 16)   // x float4 count
__global__ __launch_bounds__(256) void cvt_kernel(
    const float* __restrict__ x,
    const float* __restrict__ W1l, const float* __restrict__ W1r,
    const float* __restrict__ W2l, const float* __restrict__ W2r,
    unsigned short* __restrict__ xb, unsigned short* __restrict__ h1b,
    unsigned short* __restrict__ wb) {
    int i = blockIdx.x * 256 + threadIdx.x;
    if (i < XQ) {
        float4 v = ((const float4*)x)[i];
        ((ushort4*)xb)[i] = make_ushort4(f2bf(v.x), f2bf(v.y), f2bf(v.z), f2bf(v.w));
    } else if (i < XQ + 32) {
        int k = i - XQ;     // zero row N_NODES of both tables
        if (k < 16) ((ushort4*)xb) [(size_t)N_NODES * 16 + k]        = make_ushort4(0,0,0,0);
        else        ((ushort4*)h1b)[(size_t)N_NODES * 16 + (k - 16)] = make_ushort4(0,0,0,0);
    } else if (i < XQ + 32 + 4096) {
        int wf = i - XQ - 32;           // float4 idx over 4 matrices
        int m = wf >> 10, k = wf & 1023;
        const float* s = (m == 0) ? W1l : (m == 1) ? W1r : (m == 2) ? W2l : W2r;
        float4 v = ((const float4*)s)[k];
        ((ushort4*)wb)[(size_t)m * 1024 + k] =
            make_ushort4(f2bf(v.x), f2bf(v.y), f2bf(v.z), f2bf(v.w));
    }
}

// ---- Phase A: LDS counting-sort 4096-edge batches into 391 dst-buckets --
__global__ __launch_bounds__(512) void binA_kernel(const int* __restrict__ src,
                                                   const int* __restrict__ dst,
                                                   int* __restrict__ btail,
                                                   int* __restrict__ bucketbuf) {
    __shared__ int cntA[392];
    __shared__ int excl[512];
    __shared__ int basep[392];
    __shared__ int   stage_pk[4096];
    __shared__ short stage_bk[4096];

    const int t  = threadIdx.x;
    const int e0 = blockIdx.x * 4096;
    const int cbatch = min(4096, N_EDGES - e0);

    if (t < 392) cntA[t] = 0;
    __syncthreads();

    int mb[8], mr[8], mpk[8];
#pragma unroll
    for (int i = 0; i < 8; ++i) {
        int idx = i * 512 + t;
        mb[i] = -1;
        if (idx < cbatch) {
            int e = e0 + idx;
            int s = src[e], d = dst[e];
            int b = d >> 8;
            mb[i]  = b;
            mpk[i] = (s << 8) | (d & 255);
            mr[i]  = atomicAdd(&cntA[b], 1);
        }
    }
    __syncthreads();

    excl[t] = (t < 392) ? cntA[t] : 0;
    __syncthreads();
    for (int off = 1; off < 512; off <<= 1) {
        int u = (t >= off) ? excl[t - off] : 0;
        __syncthreads();
        excl[t] += u;
        __syncthreads();
    }
    if (t < NBUCK && cntA[t] > 0)
        basep[t] = atomicAdd(&btail[t], cntA[t]);
    __syncthreads();

#pragma unroll
    for (int i = 0; i < 8; ++i) {
        if (mb[i] >= 0) {
            int b = mb[i];
            int p = excl[b] - cntA[b] + mr[i];
            stage_pk[p] = mpk[i];
            stage_bk[p] = (short)b;
        }
    }
    __syncthreads();

#pragma unroll
    for (int i = 0; i < 8; ++i) {
        int idx = i * 512 + t;
        if (idx < cbatch) {
            int b = stage_bk[idx];
            int k = idx - (excl[b] - cntA[b]);
            int g = basep[b] + k;
            if (g < BUFCAP) bucketbuf[b * BUFCAP + g] = stage_pk[idx];
        }
    }
}

// ---- Phase B: one block per bucket; LDS-atomic counts + LDS CSR stage ---
__global__ __launch_bounds__(512) void binB_kernel(const int* __restrict__ btail,
                                                   const int* __restrict__ bucketbuf,
                                                   int* __restrict__ csr,
                                                   int* __restrict__ deg) {
    __shared__ int cur[256];
    __shared__ int lcsr[256 * CAP];   // 48 KB

    const int t = threadIdx.x;
    const int b = blockIdx.x;

    if (t < 256) cur[t] = 0;
    __syncthreads();

    int c = btail[b];
    if (c > BUFCAP) c = BUFCAP;
    const int* buf = bucketbuf + b * BUFCAP;
    for (int i = t; i < c; i += 512) {
        int pk = buf[i];
        int nl = pk & 255;
        int s  = pk >> 8;
        int r  = atomicAdd(&cur[nl], 1);
        if (r < CAP) lcsr[nl * CAP + r] = s;
    }
    __syncthreads();

    const int base = b * 256;
    for (int i = t; i < 256 * CAP; i += 512)
        csr[(size_t)base * CAP + i] = lcsr[i];
    if (t < 256) deg[base + t] = cur[t];
}

// ---- persistent fused layer: work-stealing 32-node tiles ----------------
// Gather-mean (32 groups of 8 lanes x 16 B rows) -> LDS A-tile, 4-wave MFMA
// (wave -> row-tile w&1, col-half w>>1), optional fused head.
// LAYER 1: feat=x_b, h -> h1b (bf16).  LAYER 2: feat=h1b, h -> h_out+out.
template <int LAYER>
__global__ __launch_bounds__(256, 8) void layer_kernel(
    int* __restrict__ ctr,
    const int* __restrict__ csr, const int* __restrict__ deg_g,
    const unsigned short* __restrict__ feat_b,      // N+1 rows (zero row at N)
    const unsigned short* __restrict__ wl_b,
    const float* __restrict__ bl,
    const unsigned short* __restrict__ wr_b,
    unsigned short* __restrict__ hout_b,            // LAYER==1
    float* __restrict__ hout_f,                     // LAYER==2
    const float* __restrict__ Wh, const float* __restrict__ bh,
    float* __restrict__ out)
{
    // sA/sX: bf16 [32][80] (16 B-aligned rows); sH overlays sA: f32 [32][72]
    __shared__ __align__(16) char lds[10240 + 1024 + 16];
    unsigned short* sA = (unsigned short*)lds;          // 5120 B
    unsigned short* sX = sA + 32 * 80;                  // 5120 B
    float* sH    = (float*)lds;                         // 9216 B (overlay)
    float* spart = (float*)(lds + 10240);
    int*   s_tile = (int*)(lds + 10240 + 1024);

    const int tid = threadIdx.x;
    const bf16x8* fb8 = (const bf16x8*)feat_b;          // 8 per feature row

    for (;;) {
        if (tid == 0) *s_tile = atomicAdd(ctr, 1);
        __syncthreads();
        const int tile = *s_tile;
        if (tile >= NTILES) return;
        const int n0 = tile * 32;

        // ---- stage X operand: own 32 rows, coalesced (512 ushort4 slots) ----
#pragma unroll
        for (int i = 0; i < 2; ++i) {
            int idx = tid + 256 * i;
            int row = idx >> 4, c4 = idx & 15;
            ushort4 x4 = ((const ushort4*)feat_b)[(size_t)(n0 + row) * 16 + c4];
            *(ushort4*)(sX + row * 80 + c4 * 4) = x4;
        }

        // ---- gather-mean into sA: 32 groups of 8 lanes, 16 B/lane rows ----
        const int l8  = tid & 7;
        const int grp = tid >> 3;           // 0..31
        const int n = n0 + grp;
        const int deg = deg_g[n];
        const int len = (deg < CAP) ? deg : CAP;
        const int* row = csr + (size_t)n * CAP;
        float a[8];
#pragma unroll
        for (int e = 0; e < 8; ++e) a[e] = 0.f;

        for (int cb = 0; cb < len; cb += 8) {
            int id = (cb + l8 < len) ? row[cb + l8] : N_NODES;   // OOR -> zero row
            bf16x8 v[8];
#pragma unroll
            for (int i = 0; i < 8; ++i)
                v[i] = fb8[(size_t)__shfl(id, i, 8) * 8 + l8];
#pragma unroll
            for (int i = 0; i < 8; ++i) {
#pragma unroll
                for (int e = 0; e < 8; ++e)
                    a[e] += bf2f((unsigned short)v[i][e]);
            }
        }
        float inv = 1.0f / fmaxf((float)deg, 1.0f);
        bf16x8 mv;
#pragma unroll
        for (int e = 0; e < 8; ++e) mv[e] = (short)f2bf(a[e] * inv);
        *(bf16x8*)(sA + grp * 80 + l8 * 8) = mv;
        __syncthreads();

        // ---- MFMA: wave w -> rows [16*(w&1)), cols [32*(w>>1)) ----
        const int w4 = tid >> 6;
        const int rt = w4 & 1, ch = w4 >> 1;
        const int l64 = tid & 63;
        const int rowl = l64 & 15, quad = l64 >> 4;

        const unsigned short* ab = sA + (rt * 16 + rowl) * 80 + quad * 8;
        const unsigned short* xb = sX + (rt * 16 + rowl) * 80 + quad * 8;
        bf16x8 am0 = *(const bf16x8*)(ab);
        bf16x8 am1 = *(const bf16x8*)(ab + 32);
        bf16x8 ax0 = *(const bf16x8*)(xb);
        bf16x8 ax1 = *(const bf16x8*)(xb + 32);
        __syncthreads();   // A/X consumed into regs; sH may overwrite

        f32x4 acc2[2];
        float bj2[2];
#pragma unroll
        for (int j2 = 0; j2 < 2; ++j2) {
            int jt = ch * 2 + j2;
            const unsigned short* wlp = wl_b + (jt * 16 + rowl) * 64 + quad * 8;
            const unsigned short* wrp = wr_b + (jt * 16 + rowl) * 64 + quad * 8;
            bf16x8 b0 = *(const bf16x8*)(wlp);
            bf16x8 b1 = *(const bf16x8*)(wlp + 32);
            bf16x8 b2 = *(const bf16x8*)(wrp);
            bf16x8 b3 = *(const bf16x8*)(wrp + 32);
            f32x4 acc = {0.f, 0.f, 0.f, 0.f};
            acc = __builtin_amdgcn_mfma_f32_16x16x32_bf16(am0, b0, acc, 0, 0, 0);
            acc = __builtin_amdgcn_mfma_f32_16x16x32_bf16(am1, b1, acc, 0, 0, 0);
            acc = __builtin_amdgcn_mfma_f32_16x16x32_bf16(ax0, b2, acc, 0, 0, 0);
            acc = __builtin_amdgcn_mfma_f32_16x16x32_bf16(ax1, b3, acc, 0, 0, 0);
            acc2[j2] = acc;
            bj2[j2] = bl[jt * 16 + rowl];
        }

#pragma unroll
        for (int j2 = 0; j2 < 2; ++j2) {
            int jt = ch * 2 + j2;
#pragma unroll
            for (int r = 0; r < 4; ++r) {
                int node = rt * 16 + quad * 4 + r;
                sH[node * 72 + jt * 16 + rowl] = fmaxf(acc2[j2][r] + bj2[j2], 0.f);
            }
        }
        __syncthreads();

        if (LAYER == 2) {
            int node = tid >> 3, q = tid & 7;
            float p = 0.f;
#pragma unroll
            for (int c = 0; c < 2; ++c) {
                float4 hv = *(const float4*)(sH + node * 72 + q * 8 + c * 4);
                float4 wv = ((const float4*)Wh)[q * 2 + c];
                p += hv.x * wv.x + hv.y * wv.y + hv.z * wv.z + hv.w * wv.w;
            }
            spart[tid] = p;
        }

        // ---- write h (coalesced from LDS) ----
#pragma unroll
        for (int i = 0; i < 2; ++i) {
            int idx = tid + 256 * i;
            int row = idx >> 4, c4 = idx & 15;
            int nn = n0 + row;
            const float* hp = sH + row * 72 + c4 * 4;
            if (LAYER == 1) {
                ((ushort4*)hout_b)[(size_t)nn * 16 + c4] =
                    make_ushort4(f2bf(hp[0]), f2bf(hp[1]), f2bf(hp[2]), f2bf(hp[3]));
            } else {
                ((float4*)hout_f)[(size_t)nn * 16 + c4] =
                    make_float4(hp[0], hp[1], hp[2], hp[3]);
            }
        }

        if (LAYER == 2) {
            __syncthreads();
            if (tid < 32) {
                float s = bh[0];
#pragma unroll
                for (int k = 0; k < 8; ++k) s += spart[tid * 8 + k];
                out[n0 + tid] = s;
            }
        }
    }
}

extern "C" void kernel_launch(void* const* d_in, const int* in_sizes, int n_in,
                              void* d_out, int out_size, void* d_ws, size_t ws_size,
                              hipStream_t stream) {
    const float* x   = (const float*)d_in[0];
    const int*   ei  = (const int*)d_in[1];
    const int*   src = ei;
    const int*   dst = ei + N_EDGES;
    const float* W1l = (const float*)d_in[2];
    const float* W1r = (const float*)d_in[3];
    const float* b1  = (const float*)d_in[4];
    const float* W2l = (const float*)d_in[5];
    const float* W2r = (const float*)d_in[6];
    const float* b2  = (const float*)d_in[7];
    const float* Wh  = (const float*)d_in[8];
    const float* bh  = (const float*)d_in[9];

    float* out   = (float*)d_out;        // [N]
    float* h_out = out + N_NODES;        // [N,64] final h2 (fp32)

    // ---- ws layout (ints):
    // btail[512] | ctr[2] pad to 640 | deg[NPAD] | csr | wb | x_b[N+1] | h1b[N+1]
    int* wsi   = (int*)d_ws;
    int* btail = wsi;                                   // 512 (zeroed)
    int* ctr1  = wsi + 512;                             // layer-1 tile counter
    int* ctr2  = wsi + 513;                             // layer-2 tile counter
    int* deg   = wsi + 640;                             // NPAD
    int* csr   = deg + NPAD;                            // NBUCK*256*CAP ints
    unsigned short* wb  = (unsigned short*)(csr + NBUCK * 256 * CAP);  // 16384 bf16
    unsigned short* x_b = wb + 16384;                   // (N+1)*64 bf16
    unsigned short* h1b = x_b + (size_t)(N_NODES + 1) * D;  // (N+1)*64 bf16
    int* bucketbuf = (int*)h1b;     // ALIAS: 6.4 MB; dead before layer1 writes h1b

    unsigned short* w1l_b = wb;
    unsigned short* w1r_b = wb + 4096;
    unsigned short* w2l_b = wb + 8192;
    unsigned short* w2r_b = wb + 12288;

    const int AB  = (N_EDGES + 4095) / 4096;             // 313
    const int CB  = (XQ + 32 + 4096 + 255) / 256;        // 6267

    hipMemsetAsync(btail, 0, 640 * sizeof(int), stream);

    cvt_kernel<<<CB, 256, 0, stream>>>(x, W1l, W1r, W2l, W2r, x_b, h1b, wb);

    // ---- CSR build: two-phase LDS binning ----
    binA_kernel<<<AB, 512, 0, stream>>>(src, dst, btail, bucketbuf);
    binB_kernel<<<NBUCK, 512, 0, stream>>>(btail, bucketbuf, csr, deg);

    // ---- persistent fused layers (work-stealing) ----
    layer_kernel<1><<<PERSIST, 256, 0, stream>>>(
        ctr1, csr, deg, x_b, w1l_b, b1, w1r_b, h1b, nullptr, nullptr, nullptr, nullptr);
    layer_kernel<2><<<PERSIST, 256, 0, stream>>>(
        ctr2, csr, deg, h1b, w2l_b, b2, w2r_b, nullptr, h_out, Wh, bh, out);
}

// Round 12
// 237.316 us; speedup vs baseline: 1.1558x; 1.1558x over previous
//
#include <hip/hip_runtime.h>

#define N_NODES 100000
#define N_EDGES 1280000
#define D 64
#define NPAD 102400
#define CAP 48              // per-node CSR capacity; rows 192 B (64 B-aligned)
#define NBUCK 391           // buckets of 256 nodes: 391*256 = 100096
#define BUFCAP 4096         // per-bucket edge buffer capacity (avg 3276, +12 sigma)
#define NTILES 1563         // 64-node tiles
#define PERSIST 1024        // 4 blocks/CU * 256 CUs (8 waves/block -> 32-wave cap)

typedef __attribute__((ext_vector_type(8))) short bf16x8;
typedef __attribute__((ext_vector_type(4))) float f32x4;

__device__ __forceinline__ unsigned short f2bf(float f) {
    union { float f; unsigned u; } c; c.f = f;
    unsigned u = c.u;
    return (unsigned short)((u + 0x7FFF + ((u >> 16) & 1)) >> 16);   // RNE
}
__device__ __forceinline__ float bf2f(unsigned short s) {
    union { unsigned u; float f; } c; c.u = ((unsigned)s) << 16;
    return c.f;
}

// ---- fused convert: x -> bf16, 2 zero rows, 4 weight matrices -> bf16 ---
#define XQ (N_NODES * 16)   // x float4 count
__global__ __launch_bounds__(256) void cvt_kernel(
    const float* __restrict__ x,
    const float* __restrict__ W1l, const float* __restrict__ W1r,
    const float* __restrict__ W2l, const float* __restrict__ W2r,
    unsigned short* __restrict__ xb, unsigned short* __restrict__ h1b,
    unsigned short* __restrict__ wb) {
    int i = blockIdx.x * 256 + threadIdx.x;
    if (i < XQ) {
        float4 v = ((const float4*)x)[i];
        ((ushort4*)xb)[i] = make_ushort4(f2bf(v.x), f2bf(v.y), f2bf(v.z), f2bf(v.w));
    } else if (i < XQ + 32) {
        int k = i - XQ;     // zero row N_NODES of both tables
        if (k < 16) ((ushort4*)xb) [(size_t)N_NODES * 16 + k]        = make_ushort4(0,0,0,0);
        else        ((ushort4*)h1b)[(size_t)N_NODES * 16 + (k - 16)] = make_ushort4(0,0,0,0);
    } else if (i < XQ + 32 + 4096) {
        int wf = i - XQ - 32;           // float4 idx over 4 matrices
        int m = wf >> 10, k = wf & 1023;
        const float* s = (m == 0) ? W1l : (m == 1) ? W1r : (m == 2) ? W2l : W2r;
        float4 v = ((const float4*)s)[k];
        ((ushort4*)wb)[(size_t)m * 1024 + k] =
            make_ushort4(f2bf(v.x), f2bf(v.y), f2bf(v.z), f2bf(v.w));
    }
}

// ---- Phase A: LDS counting-sort 4096-edge batches into 391 dst-buckets --
__global__ __launch_bounds__(512) void binA_kernel(const int* __restrict__ src,
                                                   const int* __restrict__ dst,
                                                   int* __restrict__ btail,
                                                   int* __restrict__ bucketbuf) {
    __shared__ int cntA[392];
    __shared__ int excl[512];
    __shared__ int basep[392];
    __shared__ int   stage_pk[4096];
    __shared__ short stage_bk[4096];

    const int t  = threadIdx.x;
    const int e0 = blockIdx.x * 4096;
    const int cbatch = min(4096, N_EDGES - e0);

    if (t < 392) cntA[t] = 0;
    __syncthreads();

    int mb[8], mr[8], mpk[8];
#pragma unroll
    for (int i = 0; i < 8; ++i) {
        int idx = i * 512 + t;
        mb[i] = -1;
        if (idx < cbatch) {
            int e = e0 + idx;
            int s = src[e], d = dst[e];
            int b = d >> 8;
            mb[i]  = b;
            mpk[i] = (s << 8) | (d & 255);
            mr[i]  = atomicAdd(&cntA[b], 1);
        }
    }
    __syncthreads();

    excl[t] = (t < 392) ? cntA[t] : 0;
    __syncthreads();
    for (int off = 1; off < 512; off <<= 1) {
        int u = (t >= off) ? excl[t - off] : 0;
        __syncthreads();
        excl[t] += u;
        __syncthreads();
    }
    if (t < NBUCK && cntA[t] > 0)
        basep[t] = atomicAdd(&btail[t], cntA[t]);
    __syncthreads();

#pragma unroll
    for (int i = 0; i < 8; ++i) {
        if (mb[i] >= 0) {
            int b = mb[i];
            int p = excl[b] - cntA[b] + mr[i];
            stage_pk[p] = mpk[i];
            stage_bk[p] = (short)b;
        }
    }
    __syncthreads();

#pragma unroll
    for (int i = 0; i < 8; ++i) {
        int idx = i * 512 + t;
        if (idx < cbatch) {
            int b = stage_bk[idx];
            int k = idx - (excl[b] - cntA[b]);
            int g = basep[b] + k;
            if (g < BUFCAP) bucketbuf[b * BUFCAP + g] = stage_pk[idx];
        }
    }
}

// ---- Phase B: one block per bucket; LDS-atomic counts + LDS CSR stage ---
__global__ __launch_bounds__(512) void binB_kernel(const int* __restrict__ btail,
                                                   const int* __restrict__ bucketbuf,
                                                   int* __restrict__ csr,
                                                   int* __restrict__ deg) {
    __shared__ int cur[256];
    __shared__ int lcsr[256 * CAP];   // 48 KB

    const int t = threadIdx.x;
    const int b = blockIdx.x;

    if (t < 256) cur[t] = 0;
    __syncthreads();

    int c = btail[b];
    if (c > BUFCAP) c = BUFCAP;
    const int* buf = bucketbuf + b * BUFCAP;
    for (int i = t; i < c; i += 512) {
        int pk = buf[i];
        int nl = pk & 255;
        int s  = pk >> 8;
        int r  = atomicAdd(&cur[nl], 1);
        if (r < CAP) lcsr[nl * CAP + r] = s;
    }
    __syncthreads();

    const int base = b * 256;
    for (int i = t; i < 256 * CAP; i += 512)
        csr[(size_t)base * CAP + i] = lcsr[i];
    if (t < 256) deg[base + t] = cur[t];
}

// ---- persistent fused layer: work-stealing 64-node tiles (R10 body) -----
// Gather-mean (32 groups of 16 lanes, 2 passes) -> LDS A-tile, 8-wave MFMA
// (wave -> row-tile w&3, col-half w>>2), optional fused head.
// LAYER 1: feat=x_b, h -> h1b (bf16).  LAYER 2: feat=h1b, h -> h_out+out.
template <int LAYER>
__global__ __launch_bounds__(512, 8) void layer_kernel(
    int* __restrict__ ctr,
    const int* __restrict__ csr, const int* __restrict__ deg_g,
    const unsigned short* __restrict__ feat_b,      // N+1 rows (zero row at N)
    const unsigned short* __restrict__ wl_b,
    const float* __restrict__ bl,
    const unsigned short* __restrict__ wr_b,
    unsigned short* __restrict__ hout_b,            // LAYER==1
    float* __restrict__ hout_f,                     // LAYER==2
    const float* __restrict__ Wh, const float* __restrict__ bh,
    float* __restrict__ out)
{
    __shared__ __align__(16) char lds[18432 + 2048 + 16];
    unsigned short* sA = (unsigned short*)lds;      // mean tile [64][72] bf16
    unsigned short* sX = sA + 64 * 72;              // root tile [64][72] bf16
    float* sH    = (float*)lds;                     // reused: h tile [64][68] f32
    float* spart = (float*)(lds + 18432);           // 512 floats
    int*   s_tile = (int*)(lds + 18432 + 2048);

    const int tid = threadIdx.x;
    const ushort4* fb = (const ushort4*)feat_b;
    const int l   = tid & 15;
    const int grp = tid >> 4;           // 0..31

    for (;;) {
        if (tid == 0) *s_tile = atomicAdd(ctr, 1);
        __syncthreads();                 // broadcast tile; also protects sX/sH reuse
        const int tile = *s_tile;
        if (tile >= NTILES) return;
        const int n0 = tile * 64;

        // ---- stage X operand: own 64 rows, coalesced ----
#pragma unroll
        for (int i = 0; i < 2; ++i) {
            int idx = tid + 512 * i;
            int row = idx >> 4, c4 = idx & 15;
            int n = n0 + row;
            ushort4 x4 = make_ushort4(0, 0, 0, 0);
            if (n < N_NODES) x4 = ((const ushort4*)feat_b)[(size_t)n * 16 + c4];
            *(ushort4*)(sX + row * 72 + c4 * 4) = x4;
        }

        // ---- gather-mean into sA: 32 groups of 16 lanes, 2 passes ----
#pragma unroll 1
        for (int p = 0; p < 2; ++p) {
            int rloc = p * 32 + grp;
            int n = n0 + rloc;
            int deg = (n < N_NODES) ? deg_g[n] : 0;
            int len = (deg < CAP) ? deg : CAP;
            const int* row = csr + (size_t)n * CAP;
            float ax = 0.f, ay = 0.f, az = 0.f, aw = 0.f;
            for (int cb = 0; cb < len; cb += 16) {
                int idxl = cb + l;
                int id = (idxl < len) ? row[idxl] : N_NODES;   // OOR -> zero row
                ushort4 v[16];
#pragma unroll
                for (int i = 0; i < 16; ++i)
                    v[i] = fb[(size_t)__shfl(id, i, 16) * 16 + l];
#pragma unroll
                for (int i = 0; i < 16; ++i) {
                    ax += bf2f(v[i].x); ay += bf2f(v[i].y);
                    az += bf2f(v[i].z); aw += bf2f(v[i].w);
                }
            }
            float inv = 1.0f / fmaxf((float)deg, 1.0f);
            *(ushort4*)(sA + rloc * 72 + l * 4) =
                make_ushort4(f2bf(ax * inv), f2bf(ay * inv), f2bf(az * inv), f2bf(aw * inv));
        }
        __syncthreads();

        // ---- MFMA: 8 waves, wave w -> rows [16*(w&3)), cols [32*(w>>2)) ----
        const int w8 = tid >> 6;
        const int rt = w8 & 3, ch = w8 >> 2;
        const int l64 = tid & 63;
        const int rowl = l64 & 15, quad = l64 >> 4;

        const unsigned short* ab = sA + (rt * 16 + rowl) * 72 + quad * 8;
        const unsigned short* xb = sX + (rt * 16 + rowl) * 72 + quad * 8;
        bf16x8 am0 = *(const bf16x8*)(ab);
        bf16x8 am1 = *(const bf16x8*)(ab + 32);
        bf16x8 ax0 = *(const bf16x8*)(xb);
        bf16x8 ax1 = *(const bf16x8*)(xb + 32);
        __syncthreads();   // A/X consumed into regs; sH may overwrite

        f32x4 acc2[2];
        float bj2[2];
#pragma unroll
        for (int j2 = 0; j2 < 2; ++j2) {
            int jt = ch * 2 + j2;
            const unsigned short* wlp = wl_b + (jt * 16 + rowl) * 64 + quad * 8;
            const unsigned short* wrp = wr_b + (jt * 16 + rowl) * 64 + quad * 8;
            bf16x8 b0 = *(const bf16x8*)(wlp);
            bf16x8 b1 = *(const bf16x8*)(wlp + 32);
            bf16x8 b2 = *(const bf16x8*)(wrp);
            bf16x8 b3 = *(const bf16x8*)(wrp + 32);
            f32x4 acc = {0.f, 0.f, 0.f, 0.f};
            acc = __builtin_amdgcn_mfma_f32_16x16x32_bf16(am0, b0, acc, 0, 0, 0);
            acc = __builtin_amdgcn_mfma_f32_16x16x32_bf16(am1, b1, acc, 0, 0, 0);
            acc = __builtin_amdgcn_mfma_f32_16x16x32_bf16(ax0, b2, acc, 0, 0, 0);
            acc = __builtin_amdgcn_mfma_f32_16x16x32_bf16(ax1, b3, acc, 0, 0, 0);
            acc2[j2] = acc;
            bj2[j2] = bl[jt * 16 + rowl];
        }

#pragma unroll
        for (int j2 = 0; j2 < 2; ++j2) {
            int jt = ch * 2 + j2;
#pragma unroll
            for (int r = 0; r < 4; ++r) {
                int node = rt * 16 + quad * 4 + r;
                sH[node * 68 + jt * 16 + rowl] = fmaxf(acc2[j2][r] + bj2[j2], 0.f);
            }
        }
        __syncthreads();

        if (LAYER == 2) {
            int node = tid >> 3, q = tid & 7;
            float p = 0.f;
#pragma unroll
            for (int c = 0; c < 2; ++c) {
                float4 hv = *(const float4*)(sH + node * 68 + q * 8 + c * 4);
                float4 wv = ((const float4*)Wh)[q * 2 + c];
                p += hv.x * wv.x + hv.y * wv.y + hv.z * wv.z + hv.w * wv.w;
            }
            spart[tid] = p;
        }

        // ---- write h (coalesced from LDS) ----
#pragma unroll
        for (int i = 0; i < 2; ++i) {
            int idx = tid + 512 * i;
            int row = idx >> 4, c4 = idx & 15;
            int n = n0 + row;
            if (n < N_NODES) {
                const float* hp = sH + row * 68 + c4 * 4;
                if (LAYER == 1) {
                    ((ushort4*)hout_b)[(size_t)n * 16 + c4] =
                        make_ushort4(f2bf(hp[0]), f2bf(hp[1]), f2bf(hp[2]), f2bf(hp[3]));
                } else {
                    ((float4*)hout_f)[(size_t)n * 16 + c4] =
                        make_float4(hp[0], hp[1], hp[2], hp[3]);
                }
            }
        }

        if (LAYER == 2) {
            __syncthreads();
            if (tid < 64) {
                int n = n0 + tid;
                if (n < N_NODES) {
                    float s = bh[0];
#pragma unroll
                    for (int k = 0; k < 8; ++k) s += spart[tid * 8 + k];
                    out[n] = s;
                }
            }
        }
    }
}

extern "C" void kernel_launch(void* const* d_in, const int* in_sizes, int n_in,
                              void* d_out, int out_size, void* d_ws, size_t ws_size,
                              hipStream_t stream) {
    const float* x   = (const float*)d_in[0];
    const int*   ei  = (const int*)d_in[1];
    const int*   src = ei;
    const int*   dst = ei + N_EDGES;
    const float* W1l = (const float*)d_in[2];
    const float* W1r = (const float*)d_in[3];
    const float* b1  = (const float*)d_in[4];
    const float* W2l = (const float*)d_in[5];
    const float* W2r = (const float*)d_in[6];
    const float* b2  = (const float*)d_in[7];
    const float* Wh  = (const float*)d_in[8];
    const float* bh  = (const float*)d_in[9];

    float* out   = (float*)d_out;        // [N]
    float* h_out = out + N_NODES;        // [N,64] final h2 (fp32)

    // ---- ws layout (ints):
    // btail[512] | ctr1,ctr2 pad to 640 | deg[NPAD] | csr | wb | x_b[N+1] | h1b[N+1]
    int* wsi   = (int*)d_ws;
    int* btail = wsi;                                   // 512 (zeroed)
    int* ctr1  = wsi + 512;                             // layer-1 tile counter
    int* ctr2  = wsi + 513;                             // layer-2 tile counter
    int* deg   = wsi + 640;                             // NPAD
    int* csr   = deg + NPAD;                            // NBUCK*256*CAP ints
    unsigned short* wb  = (unsigned short*)(csr + NBUCK * 256 * CAP);  // 16384 bf16
    unsigned short* x_b = wb + 16384;                   // (N+1)*64 bf16
    unsigned short* h1b = x_b + (size_t)(N_NODES + 1) * D;  // (N+1)*64 bf16
    int* bucketbuf = (int*)h1b;     // ALIAS: 6.4 MB; dead before layer1 writes h1b

    unsigned short* w1l_b = wb;
    unsigned short* w1r_b = wb + 4096;
    unsigned short* w2l_b = wb + 8192;
    unsigned short* w2r_b = wb + 12288;

    const int AB  = (N_EDGES + 4095) / 4096;             // 313
    const int CB  = (XQ + 32 + 4096 + 255) / 256;        // 6267

    hipMemsetAsync(btail, 0, 640 * sizeof(int), stream);

    cvt_kernel<<<CB, 256, 0, stream>>>(x, W1l, W1r, W2l, W2r, x_b, h1b, wb);

    // ---- CSR build: two-phase LDS binning ----
    binA_kernel<<<AB, 512, 0, stream>>>(src, dst, btail, bucketbuf);
    binB_kernel<<<NBUCK, 512, 0, stream>>>(btail, bucketbuf, csr, deg);

    // ---- persistent fused layers (work-stealing 64-node tiles) ----
    layer_kernel<1><<<PERSIST, 512, 0, stream>>>(
        ctr1, csr, deg, x_b, w1l_b, b1, w1r_b, h1b, nullptr, nullptr, nullptr, nullptr);
    layer_kernel<2><<<PERSIST, 512, 0, stream>>>(
        ctr2, csr, deg, h1b, w2l_b, b2, w2r_b, nullptr, h_out, Wh, bh, out);
}

// Round 14
// 196.302 us; speedup vs baseline: 1.3973x; 1.2089x over previous
//
#include <hip/hip_runtime.h>

#define N_NODES 100000
#define N_EDGES 1280000
#define D 64
#define NPAD 102400
#define CAP 48              // per-node CSR capacity; rows 192 B
#define NBUCK 391           // buckets of 256 nodes: 391*256 = 100096
#define AB 313              // binA blocks: 4096-edge batches (last = 2048)
#define CVB 1024            // cvt role blocks inside prep kernel
#define NTILES 1563         // 64-node tiles
#define XQ (N_NODES * 16)   // x float4 count

typedef __attribute__((ext_vector_type(8))) short bf16x8;
typedef __attribute__((ext_vector_type(4))) float f32x4;

__device__ __forceinline__ unsigned short f2bf(float f) {
    union { float f; unsigned u; } c; c.f = f;
    unsigned u = c.u;
    return (unsigned short)((u + 0x7FFF + ((u >> 16) & 1)) >> 16);   // RNE
}
__device__ __forceinline__ float bf2f(unsigned short s) {
    union { unsigned u; float f; } c; c.u = ((unsigned)s) << 16;
    return c.f;
}

// ---- prep: bid<AB -> binA (atomic-free, per-block output); else cvt ----
// binA: LDS counting-sort its 4096-edge batch by bucket (dst>>8); write
//   sorted[bid*4096 + i] (bucket-sorted, coalesced) and
//   exclT[bid*392 + b] = exclusive start of bucket b within this block.
// cvt: grid-stride convert x->bf16, write zero rows, weights->bf16.
__global__ __launch_bounds__(512) void prep_kernel(
    const float* __restrict__ x,
    const int* __restrict__ src, const int* __restrict__ dst,
    const float* __restrict__ W1l, const float* __restrict__ W1r,
    const float* __restrict__ W2l, const float* __restrict__ W2r,
    unsigned short* __restrict__ xb, unsigned short* __restrict__ h1b,
    unsigned short* __restrict__ wb,
    int* __restrict__ sorted, int* __restrict__ exclT)
{
    __shared__ int cntA[392];
    __shared__ int excl[512];
    __shared__ int stage_pk[4096];

    const int t   = threadIdx.x;
    const int bid = blockIdx.x;

    if (bid < AB) {
        const int e0 = bid * 4096;
        const int cbatch = min(4096, N_EDGES - e0);

        if (t < 392) cntA[t] = 0;
        __syncthreads();

        int mb[8], mr[8], mpk[8];
#pragma unroll
        for (int i = 0; i < 8; ++i) {
            int idx = i * 512 + t;
            mb[i] = -1;
            if (idx < cbatch) {
                int e = e0 + idx;
                int s = src[e], d = dst[e];
                int b = d >> 8;
                mb[i]  = b;
                mpk[i] = (s << 8) | (d & 255);
                mr[i]  = atomicAdd(&cntA[b], 1);    // LDS atomic only
            }
        }
        __syncthreads();

        excl[t] = (t < 392) ? cntA[t] : 0;          // inclusive scan (392 used)
        __syncthreads();
        for (int off = 1; off < 512; off <<= 1) {
            int u = (t >= off) ? excl[t - off] : 0;
            __syncthreads();
            excl[t] += u;
            __syncthreads();
        }

#pragma unroll
        for (int i = 0; i < 8; ++i) {
            if (mb[i] >= 0) {
                int b = mb[i];
                stage_pk[excl[b] - cntA[b] + mr[i]] = mpk[i];
            }
        }
        __syncthreads();

#pragma unroll
        for (int i = 0; i < 8; ++i) {               // coalesced block-own write
            int idx = i * 512 + t;
            if (idx < cbatch) sorted[e0 + idx] = stage_pk[idx];
        }
        if (t < 392) exclT[bid * 392 + t] = excl[t] - cntA[t];  // exclusive starts
    } else {
        // ---- cvt role ----
        const int gtid = (bid - AB) * 512 + t;
        const int gsz  = CVB * 512;
        const int TOT  = XQ + 32 + 4096;
        for (int i = gtid; i < TOT; i += gsz) {
            if (i < XQ) {
                float4 v = ((const float4*)x)[i];
                ((ushort4*)xb)[i] = make_ushort4(f2bf(v.x), f2bf(v.y), f2bf(v.z), f2bf(v.w));
            } else if (i < XQ + 32) {
                int k = i - XQ;     // zero row N_NODES of both feature tables
                if (k < 16) ((ushort4*)xb) [(size_t)N_NODES * 16 + k]        = make_ushort4(0,0,0,0);
                else        ((ushort4*)h1b)[(size_t)N_NODES * 16 + (k - 16)] = make_ushort4(0,0,0,0);
            } else {
                int wf = i - XQ - 32;
                int m = wf >> 10, k = wf & 1023;
                const float* s = (m == 0) ? W1l : (m == 1) ? W1r : (m == 2) ? W2l : W2r;
                float4 v = ((const float4*)s)[k];
                ((ushort4*)wb)[m * 1024 + k] =
                    make_ushort4(f2bf(v.x), f2bf(v.y), f2bf(v.z), f2bf(v.w));
            }
        }
    }
}

// ---- binB: one block per bucket; merge 313 per-block segments ----------
__global__ __launch_bounds__(512) void binB_kernel(const int* __restrict__ sorted,
                                                   const int* __restrict__ exclT,
                                                   int* __restrict__ csr,
                                                   int* __restrict__ deg) {
    __shared__ int cur[256];
    __shared__ int lcsr[256 * CAP];     // 48 KB
    __shared__ int scan[512];
    __shared__ int segstart[314];       // output offsets + sentinel
    __shared__ int segsrc[313];         // source index of each segment

    const int t = threadIdx.x;
    const int k = blockIdx.x;

    if (t < 256) cur[t] = 0;

    int cnt = 0, s0 = 0;
    if (t < AB) {
        s0  = exclT[t * 392 + k];
        cnt = exclT[t * 392 + k + 1] - s0;
    }
    scan[t] = (t < AB) ? cnt : 0;
    __syncthreads();
    for (int off = 1; off < 512; off <<= 1) {       // inclusive scan over 313
        int u = (t >= off) ? scan[t - off] : 0;
        __syncthreads();
        scan[t] += u;
        __syncthreads();
    }
    if (t < AB) {
        segstart[t] = scan[t] - cnt;
        segsrc[t]   = t * 4096 + s0;
    }
    if (t == AB - 1) segstart[AB] = scan[AB - 1];   // total
    __syncthreads();

    const int Tk = segstart[AB];
    for (int i = t; i < Tk; i += 512) {
        int lo = 0, hi = AB;            // find last b with segstart[b] <= i
        while (hi - lo > 1) {
            int mid = (lo + hi) >> 1;
            if (segstart[mid] <= i) lo = mid; else hi = mid;
        }
        int pk = sorted[segsrc[lo] + (i - segstart[lo])];
        int nl = pk & 255;
        int s  = pk >> 8;
        int r  = atomicAdd(&cur[nl], 1);
        if (r < CAP) lcsr[nl * CAP + r] = s;
    }
    __syncthreads();

    const int base = k * 256;
    for (int i = t; i < 256 * CAP; i += 512)
        csr[(size_t)base * CAP + i] = lcsr[i];
    if (t < 256) deg[base + t] = cur[t];
}

// ---- fused layer (R10 body, plain grid-indexed tiles) -------------------
// Gather-mean (32 groups of 16 lanes, 2 passes) -> LDS A-tile, 8-wave MFMA
// (wave -> row-tile w&3, col-half w>>2), optional fused head.
template <int LAYER>
__global__ __launch_bounds__(512) void layer_kernel(
    const int* __restrict__ csr, const int* __restrict__ deg_g,
    const unsigned short* __restrict__ feat_b,      // N+1 rows (zero row at N)
    const unsigned short* __restrict__ wl_b,
    const float* __restrict__ bl,
    const unsigned short* __restrict__ wr_b,
    unsigned short* __restrict__ hout_b,            // LAYER==1
    float* __restrict__ hout_f,                     // LAYER==2
    const float* __restrict__ Wh, const float* __restrict__ bh,
    float* __restrict__ out)
{
    __shared__ __align__(16) char lds[18432 + 2048];
    unsigned short* sA = (unsigned short*)lds;      // mean tile [64][72] bf16
    unsigned short* sX = sA + 64 * 72;              // root tile [64][72] bf16
    float* sH    = (float*)lds;                     // reused: h tile [64][68] f32
    float* spart = (float*)(lds + 18432);           // 512 floats

    const int tid = threadIdx.x;
    const int n0  = blockIdx.x * 64;

#pragma unroll
    for (int i = 0; i < 2; ++i) {
        int idx = tid + 512 * i;
        int row = idx >> 4, c4 = idx & 15;
        int n = n0 + row;
        ushort4 x4 = make_ushort4(0, 0, 0, 0);
        if (n < N_NODES) x4 = ((const ushort4*)feat_b)[(size_t)n * 16 + c4];
        *(ushort4*)(sX + row * 72 + c4 * 4) = x4;
    }

    const ushort4* fb = (const ushort4*)feat_b;
    const int l   = tid & 15;
    const int grp = tid >> 4;           // 0..31
#pragma unroll 1
    for (int p = 0; p < 2; ++p) {
        int rloc = p * 32 + grp;
        int n = n0 + rloc;
        int deg = (n < N_NODES) ? deg_g[n] : 0;
        int len = (deg < CAP) ? deg : CAP;
        const int* row = csr + (size_t)n * CAP;
        float ax = 0.f, ay = 0.f, az = 0.f, aw = 0.f;
        for (int cb = 0; cb < len; cb += 16) {
            int idxl = cb + l;
            int id = (idxl < len) ? row[idxl] : N_NODES;   // OOR -> zero row
            ushort4 v[16];
#pragma unroll
            for (int i = 0; i < 16; ++i)
                v[i] = fb[(size_t)__shfl(id, i, 16) * 16 + l];
#pragma unroll
            for (int i = 0; i < 16; ++i) {
                ax += bf2f(v[i].x); ay += bf2f(v[i].y);
                az += bf2f(v[i].z); aw += bf2f(v[i].w);
            }
        }
        float inv = 1.0f / fmaxf((float)deg, 1.0f);
        *(ushort4*)(sA + rloc * 72 + l * 4) =
            make_ushort4(f2bf(ax * inv), f2bf(ay * inv), f2bf(az * inv), f2bf(aw * inv));
    }
    __syncthreads();

    const int w8 = tid >> 6;
    const int rt = w8 & 3, ch = w8 >> 2;
    const int l64 = tid & 63;
    const int rowl = l64 & 15, quad = l64 >> 4;

    const unsigned short* ab = sA + (rt * 16 + rowl) * 72 + quad * 8;
    const unsigned short* xb = sX + (rt * 16 + rowl) * 72 + quad * 8;
    bf16x8 am0 = *(const bf16x8*)(ab);
    bf16x8 am1 = *(const bf16x8*)(ab + 32);
    bf16x8 ax0 = *(const bf16x8*)(xb);
    bf16x8 ax1 = *(const bf16x8*)(xb + 32);
    __syncthreads();   // A/X consumed into regs; sH may overwrite

    f32x4 acc2[2];
    float bj2[2];
#pragma unroll
    for (int j2 = 0; j2 < 2; ++j2) {
        int jt = ch * 2 + j2;
        const unsigned short* wlp = wl_b + (jt * 16 + rowl) * 64 + quad * 8;
        const unsigned short* wrp = wr_b + (jt * 16 + rowl) * 64 + quad * 8;
        bf16x8 b0 = *(const bf16x8*)(wlp);
        bf16x8 b1 = *(const bf16x8*)(wlp + 32);
        bf16x8 b2 = *(const bf16x8*)(wrp);
        bf16x8 b3 = *(const bf16x8*)(wrp + 32);
        f32x4 acc = {0.f, 0.f, 0.f, 0.f};
        acc = __builtin_amdgcn_mfma_f32_16x16x32_bf16(am0, b0, acc, 0, 0, 0);
        acc = __builtin_amdgcn_mfma_f32_16x16x32_bf16(am1, b1, acc, 0, 0, 0);
        acc = __builtin_amdgcn_mfma_f32_16x16x32_bf16(ax0, b2, acc, 0, 0, 0);
        acc = __builtin_amdgcn_mfma_f32_16x16x32_bf16(ax1, b3, acc, 0, 0, 0);
        acc2[j2] = acc;
        bj2[j2] = bl[jt * 16 + rowl];
    }

#pragma unroll
    for (int j2 = 0; j2 < 2; ++j2) {
        int jt = ch * 2 + j2;
#pragma unroll
        for (int r = 0; r < 4; ++r) {
            int node = rt * 16 + quad * 4 + r;
            sH[node * 68 + jt * 16 + rowl] = fmaxf(acc2[j2][r] + bj2[j2], 0.f);
        }
    }
    __syncthreads();

    if (LAYER == 2) {
        int node = tid >> 3, q = tid & 7;
        float p = 0.f;
#pragma unroll
        for (int c = 0; c < 2; ++c) {
            float4 hv = *(const float4*)(sH + node * 68 + q * 8 + c * 4);
            float4 wv = ((const float4*)Wh)[q * 2 + c];
            p += hv.x * wv.x + hv.y * wv.y + hv.z * wv.z + hv.w * wv.w;
        }
        spart[tid] = p;
    }

#pragma unroll
    for (int i = 0; i < 2; ++i) {
        int idx = tid + 512 * i;
        int row = idx >> 4, c4 = idx & 15;
        int n = n0 + row;
        if (n < N_NODES) {
            const float* hp = sH + row * 68 + c4 * 4;
            if (LAYER == 1) {
                ((ushort4*)hout_b)[(size_t)n * 16 + c4] =
                    make_ushort4(f2bf(hp[0]), f2bf(hp[1]), f2bf(hp[2]), f2bf(hp[3]));
            } else {
                ((float4*)hout_f)[(size_t)n * 16 + c4] =
                    make_float4(hp[0], hp[1], hp[2], hp[3]);
            }
        }
    }

    if (LAYER == 2) {
        __syncthreads();
        if (tid < 64) {
            int n = n0 + tid;
            if (n < N_NODES) {
                float s = bh[0];
#pragma unroll
                for (int k = 0; k < 8; ++k) s += spart[tid * 8 + k];
                out[n] = s;
            }
        }
    }
}

extern "C" void kernel_launch(void* const* d_in, const int* in_sizes, int n_in,
                              void* d_out, int out_size, void* d_ws, size_t ws_size,
                              hipStream_t stream) {
    const float* x   = (const float*)d_in[0];
    const int*   ei  = (const int*)d_in[1];
    const int*   src = ei;
    const int*   dst = ei + N_EDGES;
    const float* W1l = (const float*)d_in[2];
    const float* W1r = (const float*)d_in[3];
    const float* b1  = (const float*)d_in[4];
    const float* W2l = (const float*)d_in[5];
    const float* W2r = (const float*)d_in[6];
    const float* b2  = (const float*)d_in[7];
    const float* Wh  = (const float*)d_in[8];
    const float* bh  = (const float*)d_in[9];

    float* out   = (float*)d_out;        // [N]
    float* h_out = out + N_NODES;        // [N,64] final h2 (fp32)

    // ---- ws layout (ints): deg[NPAD] | csr | wb | x_b[N+1] | h1b[N+1]
    // sorted/exclT alias the h1b region (dead before layer1 writes h1b;
    // h1b zero row @ +12.8 MB is beyond their 5.62 MB).
    int* wsi = (int*)d_ws;
    int* deg = wsi;                                     // NPAD
    int* csr = deg + NPAD;                              // NBUCK*256*CAP ints
    unsigned short* wb  = (unsigned short*)(csr + NBUCK * 256 * CAP);  // 16384 bf16
    unsigned short* x_b = wb + 16384;                   // (N+1)*64 bf16
    unsigned short* h1b = x_b + (size_t)(N_NODES + 1) * D;  // (N+1)*64 bf16
    int* sorted = (int*)h1b;                            // AB*4096 = 1,282,048 ints
    int* exclT  = sorted + AB * 4096;                   // AB*392  =   122,696 ints

    unsigned short* w1l_b = wb;
    unsigned short* w1r_b = wb + 4096;
    unsigned short* w2l_b = wb + 8192;
    unsigned short* w2r_b = wb + 12288;

    // 4 dispatches total — no memset, no global atomics in CSR build.
    prep_kernel<<<AB + CVB, 512, 0, stream>>>(
        x, src, dst, W1l, W1r, W2l, W2r, x_b, h1b, wb, sorted, exclT);

    binB_kernel<<<NBUCK, 512, 0, stream>>>(sorted, exclT, csr, deg);

    layer_kernel<1><<<NTILES, 512, 0, stream>>>(
        csr, deg, x_b, w1l_b, b1, w1r_b, h1b, nullptr, nullptr, nullptr, nullptr);
    layer_kernel<2><<<NTILES, 512, 0, stream>>>(
        csr, deg, h1b, w2l_b, b2, w2r_b, nullptr, h_out, Wh, bh, out);
}